// Round 6
// baseline (149.024 us; speedup 1.0000x reference)
//
#include <hip/hip_runtime.h>
#include <hip/hip_bf16.h>

// Gemma4AudioRelativePosition — fused bf16-MFMA, round 6.
// out[b,h,n,s,c] = sum_d q[s,d]*k[c,d] + (0<=c-s<=127 ? BD[s,c-s] : 0)
// R6: barrier-minimal wave-private decomposition. 512-thread blocks, 8 waves.
//  - Wave w stages K rows [32w,32w+32) into ITS OWN Klds region (only reader)
//    -> K staging needs no sync.
//  - Wave w packs Q stripe s in [16w,16w+16) to shared Qlds + computes BD for
//    that stripe (private MFMA, skew-stored to BDs).
//  - ONE __syncthreads publishes Qlds+BDs. After it: zero global loads, waves
//    free-run over (cj in {2w,2w+1}) x (st 0..7): LDS reads + MFMA + stores.
//  - LDS 80KB = BDs 32 + Klds 32 + Qlds 16 -> 2 blocks/CU = 16 waves/CU.

typedef __bf16 bf16x8 __attribute__((ext_vector_type(8)));
typedef unsigned short u16x8 __attribute__((ext_vector_type(8)));
typedef unsigned int u32x4 __attribute__((ext_vector_type(4)));
typedef float f32x4 __attribute__((ext_vector_type(4)));

__device__ __forceinline__ unsigned short f2bf(float f) {
    unsigned u = __float_as_uint(f);
    u = (u + 0x7FFFu + ((u >> 16) & 1u)) >> 16;   // RNE
    return (unsigned short)u;
}
__device__ __forceinline__ float bf2f(unsigned short s) {
    return __uint_as_float(((unsigned)s) << 16);
}
// truncation pack: two fp32 -> packed 2x bf16
__device__ __forceinline__ unsigned pk2(float a, float b) {
    return (__float_as_uint(a) >> 16) | (__float_as_uint(b) & 0xFFFF0000u);
}

// ---------------- kernel 1: proj = sin_emb @ W_pos^T  (bf16 out) ----------------
// grid 1024 = (p 0..127) x (jq 0..7); block computes proj[p, jq*64 .. jq*64+64)
__global__ __launch_bounds__(256) void proj_kernel(const float* __restrict__ W,
                                                   unsigned short* __restrict__ projw) {
    __shared__ float se[512];
    int bid = blockIdx.x;
    int p  = bid >> 3;      // 0..127
    int jq = bid & 7;       // 0..7
    int t = threadIdx.x;    // 0..255
    const float LOGINC = (float)(9.210340371976184 / 255.0);  // ln(1e4)/255
    float pos = (float)(127 - p);
    float inv = expf(-LOGINC * (float)t);
    float ang = pos * inv;
    se[t]       = sinf(ang);
    se[t + 256] = cosf(ang);
    __syncthreads();
    int j  = jq * 64 + (t >> 2);
    int tq = t & 3;
    const float4* wr = (const float4*)(W + (size_t)j * 512 + tq * 128);
    const float4* sr = (const float4*)(se + tq * 128);
    float a = 0.f;
#pragma unroll
    for (int i = 0; i < 32; ++i) {
        float4 wv = wr[i];
        float4 sv = sr[i];
        a += sv.x * wv.x + sv.y * wv.y + sv.z * wv.z + sv.w * wv.w;
    }
    a += __shfl_xor(a, 1);
    a += __shfl_xor(a, 2);
    if (tq == 0) projw[p * 512 + j] = f2bf(a);
}

// ---------------- kernel 2: fused AC + skewed BD (1 barrier, 8 waves) ----------
__global__ __launch_bounds__(512, 4) void fused_kernel(const float* __restrict__ Q,
                                                       const float* __restrict__ Kg,
                                                       const unsigned short* __restrict__ projw,
                                                       float* __restrict__ out) {
    __shared__ unsigned short BDs[128 * 128];   // BD[s][(s+p)&127] bf16 swz (32KB)
    __shared__ unsigned short Klds[256 * 64];   // all 256 K rows bf16 swz (32KB)
    __shared__ unsigned short Qlds[8 * 2 * 64 * 8]; // [st][kk][lane] 16B frags (16KB)

    // XCD-aware remap (kept from R5): h fastest within an XCD's range.
    int bid = blockIdx.x;
    int wid = (bid & 7) * 256 + (bid >> 3);   // 2048 blocks = 8 XCD x 256
    int h = wid & 7;
    int n = (wid >> 3) & 63;
    int b = wid >> 9;

    const float* qbase = Q  + ((size_t)(b * 64 + n) * 128) * 512 + h * 64;
    const float* kbase = Kg + ((size_t)(b * 64 + n) * 256) * 512 + h * 64;

    int tid = threadIdx.x;
    int w  = tid >> 6;     // wave 0..7
    int l  = tid & 63;
    int lo = l & 15;
    int hi = l >> 4;
    int rq = l >> 4;       // 0..3: row-in-quad for K staging
    int cq = l & 15;       // 0..15: float4 col slot for K staging

    // ---- issue K loads FIRST (own rows [32w,32w+32), 4 rows x 256B per instr)
    float4 kpre[8];
#pragma unroll
    for (int it = 0; it < 8; ++it) {
        int row = w * 32 + it * 4 + rq;
        kpre[it] = *(const float4*)(kbase + (size_t)row * 512 + cq * 4);
    }

    // ---- Q fragments for own stripe s in [16w,16w+16), pack RNE, publish to Qlds
    bf16x8 afrag[2];
    {
        const float* ar = qbase + (size_t)(w * 16 + lo) * 512;
#pragma unroll
        for (int kk = 0; kk < 2; ++kk) {
            float4 va = *(const float4*)(ar + kk * 32 + hi * 8);
            float4 vb = *(const float4*)(ar + kk * 32 + hi * 8 + 4);
            u16x8 u;
            u[0] = f2bf(va.x); u[1] = f2bf(va.y); u[2] = f2bf(va.z); u[3] = f2bf(va.w);
            u[4] = f2bf(vb.x); u[5] = f2bf(vb.y); u[6] = f2bf(vb.z); u[7] = f2bf(vb.w);
            afrag[kk] = __builtin_bit_cast(bf16x8, u);
            *(bf16x8*)&Qlds[((w * 2 + kk) * 64 + l) * 8] = afrag[kk];
        }
    }

    // ---- BD phase (private): BD = proj @ A^T -> col(lo)=s, row(hi*4+jr)=p.
    const unsigned short* pbase = projw + h * 64;
    int s_own = w * 16 + lo;
#pragma unroll 2
    for (int pj = 0; pj < 8; ++pj) {
        int prow = pj * 16 + lo;
        const unsigned short* pr = pbase + (size_t)prow * 512;
        bf16x8 pf0 = *(const bf16x8*)(pr + hi * 8);
        bf16x8 pf1 = *(const bf16x8*)(pr + 32 + hi * 8);
        f32x4 acc = {0.f, 0.f, 0.f, 0.f};
        acc = __builtin_amdgcn_mfma_f32_16x16x32_bf16(pf0, afrag[0], acc, 0, 0, 0);
        acc = __builtin_amdgcn_mfma_f32_16x16x32_bf16(pf1, afrag[1], acc, 0, 0, 0);
        int pb = pj * 16 + hi * 4;
#pragma unroll
        for (int jr = 0; jr < 4; ++jr) {
            int cw = (s_own + pb + jr) & 127;   // 128-wide band -> mod-128 bijection
            BDs[s_own * 128 + (cw ^ ((s_own & 7) << 3))] = f2bf(acc[jr]);
        }
    }

    // ---- stage own K rows to own Klds region (swizzled); no sync needed for K.
#pragma unroll
    for (int it = 0; it < 8; ++it) {
        int row = w * 32 + it * 4 + rq;
        float4 v = kpre[it];
        uint2 pk;
        pk.x = pk2(v.x, v.y);
        pk.y = pk2(v.z, v.w);
        *reinterpret_cast<uint2*>(&Klds[row * 64 + ((cq * 4) ^ ((row & 7) << 3))]) = pk;
    }

    __syncthreads();   // the ONLY barrier: publishes Qlds + BDs (K is private)

    // ---- free-run AC: cj in {2w, 2w+1}, st 0..7. No global loads remain.
    size_t obase = ((size_t)((b * 8 + h) * 64 + n)) * (128 * 256);
#pragma unroll
    for (int cjl = 0; cjl < 2; ++cjl) {
        int cj = w * 2 + cjl;
        int krow = cj * 16 + lo;
        bf16x8 kf0 = *(const bf16x8*)&Klds[krow * 64 + ((hi * 8)      ^ ((krow & 7) << 3))];
        bf16x8 kf1 = *(const bf16x8*)&Klds[krow * 64 + ((32 + hi * 8) ^ ((krow & 7) << 3))];
        int cb = cj * 16 + hi * 4;
#pragma unroll
        for (int st = 0; st < 8; ++st) {
            bf16x8 af0 = *(const bf16x8*)&Qlds[((st * 2 + 0) * 64 + l) * 8];
            bf16x8 af1 = *(const bf16x8*)&Qlds[((st * 2 + 1) * 64 + l) * 8];
            f32x4 acc = {0.f, 0.f, 0.f, 0.f};
            acc = __builtin_amdgcn_mfma_f32_16x16x32_bf16(kf0, af0, acc, 0, 0, 0);
            acc = __builtin_amdgcn_mfma_f32_16x16x32_bf16(kf1, af1, acc, 0, 0, 0);
            int s = st * 16 + lo;
            if (cj >= st && cj <= st + 8) {     // band-active (uniform per wave)
                uint2 pk = *(const uint2*)&BDs[s * 128 + ((cb & 127) ^ ((s & 7) << 3))];
                unsigned short v0 = (unsigned short)(pk.x & 0xffffu);
                unsigned short v1 = (unsigned short)(pk.x >> 16);
                unsigned short v2 = (unsigned short)(pk.y & 0xffffu);
                unsigned short v3 = (unsigned short)(pk.y >> 16);
                if ((unsigned)(cb + 0 - s) < 128u) acc[0] += bf2f(v0);
                if ((unsigned)(cb + 1 - s) < 128u) acc[1] += bf2f(v1);
                if ((unsigned)(cb + 2 - s) < 128u) acc[2] += bf2f(v2);
                if ((unsigned)(cb + 3 - s) < 128u) acc[3] += bf2f(v3);
            }
            *reinterpret_cast<float4*>(&out[obase + (size_t)s * 256 + cb]) =
                *reinterpret_cast<float4*>(&acc);
        }
    }
}

extern "C" void kernel_launch(void* const* d_in, const int* in_sizes, int n_in,
                              void* d_out, int out_size, void* d_ws, size_t ws_size,
                              hipStream_t stream) {
    const float* Q  = (const float*)d_in[0];
    const float* Kg = (const float*)d_in[1];
    const float* W  = (const float*)d_in[2];
    float* out = (float*)d_out;
    unsigned short* projw = (unsigned short*)d_ws;   // 128*512 bf16 = 128 KB

    hipLaunchKernelGGL(proj_kernel, dim3(1024), dim3(256), 0, stream, W, projw);
    hipLaunchKernelGGL(fused_kernel, dim3(2048), dim3(512), 0, stream, Q, Kg, projw, out);
}

// Round 7
// 136.560 us; speedup vs baseline: 1.0913x; 1.0913x over previous
//
#include <hip/hip_runtime.h>
#include <hip/hip_bf16.h>

// Gemma4AudioRelativePosition — fused bf16-MFMA, round 7.
// out[b,h,n,s,c] = sum_d q[s,d]*k[c,d] + (0<=c-s<=127 ? BD[s,c-s] : 0)
// R7 = R5 (best, 131us) with a deeper pipeline at SAME occupancy:
//  - K chunks 32 rows x 8, Klds double-buffered 2x4KB -> ONE barrier per chunk
//    (write buf[ch&1]; last reader of that buf was compute(ch-2), which
//    precedes barrier(ch-1) -> race-free).
//  - Register prefetch 2 chunks deep (kpre[2] sets, statically rotated by a
//    fully-unrolled ch loop) -> ~1 full chunk period of HBM latency slack.
//  - Q loads issued before K so afrag packing's vmcnt doesn't wait on K queue.
//  - LDS = 32KB BDs + 8KB Klds = 40KB -> 4 blocks/CU = 16 waves/CU (as R5).

typedef __bf16 bf16x8 __attribute__((ext_vector_type(8)));
typedef unsigned short u16x8 __attribute__((ext_vector_type(8)));
typedef unsigned int u32x4 __attribute__((ext_vector_type(4)));
typedef float f32x4 __attribute__((ext_vector_type(4)));

__device__ __forceinline__ unsigned short f2bf(float f) {
    unsigned u = __float_as_uint(f);
    u = (u + 0x7FFFu + ((u >> 16) & 1u)) >> 16;   // RNE
    return (unsigned short)u;
}
__device__ __forceinline__ float bf2f(unsigned short s) {
    return __uint_as_float(((unsigned)s) << 16);
}
// truncation pack: two fp32 -> packed 2x bf16
__device__ __forceinline__ unsigned pk2(float a, float b) {
    return (__float_as_uint(a) >> 16) | (__float_as_uint(b) & 0xFFFF0000u);
}

// ---------------- kernel 1: proj = sin_emb @ W_pos^T  (bf16 out) ----------------
// grid 1024 = (p 0..127) x (jq 0..7); block computes proj[p, jq*64 .. jq*64+64)
__global__ __launch_bounds__(256) void proj_kernel(const float* __restrict__ W,
                                                   unsigned short* __restrict__ projw) {
    __shared__ float se[512];
    int bid = blockIdx.x;
    int p  = bid >> 3;      // 0..127
    int jq = bid & 7;       // 0..7
    int t = threadIdx.x;    // 0..255
    const float LOGINC = (float)(9.210340371976184 / 255.0);  // ln(1e4)/255
    float pos = (float)(127 - p);
    float inv = expf(-LOGINC * (float)t);
    float ang = pos * inv;
    se[t]       = sinf(ang);
    se[t + 256] = cosf(ang);
    __syncthreads();
    int j  = jq * 64 + (t >> 2);
    int tq = t & 3;
    const float4* wr = (const float4*)(W + (size_t)j * 512 + tq * 128);
    const float4* sr = (const float4*)(se + tq * 128);
    float a = 0.f;
#pragma unroll
    for (int i = 0; i < 32; ++i) {
        float4 wv = wr[i];
        float4 sv = sr[i];
        a += sv.x * wv.x + sv.y * wv.y + sv.z * wv.z + sv.w * wv.w;
    }
    a += __shfl_xor(a, 1);
    a += __shfl_xor(a, 2);
    if (tq == 0) projw[p * 512 + j] = f2bf(a);
}

// ---------------- kernel 2: fused AC + skewed BD ----------------
__global__ __launch_bounds__(256, 4) void fused_kernel(const float* __restrict__ Q,
                                                       const float* __restrict__ Kg,
                                                       const unsigned short* __restrict__ projw,
                                                       float* __restrict__ out) {
    __shared__ unsigned short BDs[128 * 128];     // BD[s][(s+p)&127] bf16 swz (32KB)
    __shared__ unsigned short Klds[2][32 * 64];   // double-buffered 32-row chunks (8KB)

    // XCD-aware remap: h fastest within an XCD's range -> h-siblings share L2.
    int bid = blockIdx.x;
    int wid = (bid & 7) * 256 + (bid >> 3);   // 2048 blocks = 8 XCD x 256
    int h = wid & 7;
    int n = (wid >> 3) & 63;
    int b = wid >> 9;

    const float* qbase = Q  + ((size_t)(b * 64 + n) * 128) * 512 + h * 64;
    const float* kbase = Kg + ((size_t)(b * 64 + n) * 256) * 512 + h * 64;

    int tid = threadIdx.x;
    int w  = tid >> 6;     // wave 0..3 -> s-stripe [32w, 32w+32)
    int l  = tid & 63;
    int lo = l & 15;
    int hi = l >> 4;
    int rq = l >> 4;       // 0..3: row-in-quad for K staging
    int cq = l & 15;       // 0..15: float4 col slot (4 rows x 256B per instr)

    // ---- Q loads FIRST (their vmcnt wait won't include the K queue)
    float4 qv[4];
    {
        const float* ar = qbase + (size_t)(w * 32 + 0 * 16 + lo) * 512;  // i2=0 row
        qv[0] = *(const float4*)(ar + 0 * 32 + hi * 8);
        qv[1] = *(const float4*)(ar + 0 * 32 + hi * 8 + 4);
        qv[2] = *(const float4*)(ar + 1 * 32 + hi * 8);
        qv[3] = *(const float4*)(ar + 1 * 32 + hi * 8 + 4);
    }
    float4 qv2[4];
    {
        const float* ar = qbase + (size_t)(w * 32 + 1 * 16 + lo) * 512;  // i2=1 row
        qv2[0] = *(const float4*)(ar + 0 * 32 + hi * 8);
        qv2[1] = *(const float4*)(ar + 0 * 32 + hi * 8 + 4);
        qv2[2] = *(const float4*)(ar + 1 * 32 + hi * 8);
        qv2[3] = *(const float4*)(ar + 1 * 32 + hi * 8 + 4);
    }

    // ---- K prefetch, 2 chunks deep (chunk = 32 rows; 2 float4/thread each)
    float4 kpre[2][2];
#pragma unroll
    for (int it = 0; it < 2; ++it) {
        int row = w * 8 + it * 4 + rq;
        kpre[0][it] = *(const float4*)(kbase + (size_t)(0 * 32 + row) * 512 + cq * 4);
    }
#pragma unroll
    for (int it = 0; it < 2; ++it) {
        int row = w * 8 + it * 4 + rq;
        kpre[1][it] = *(const float4*)(kbase + (size_t)(1 * 32 + row) * 512 + cq * 4);
    }

    // ---- pack A-fragments (waits only on Q loads)
    bf16x8 afrag[2][2];
#pragma unroll
    for (int kk = 0; kk < 2; ++kk) {
        float4 va = qv[kk * 2], vb = qv[kk * 2 + 1];
        u16x8 u;
        u[0] = f2bf(va.x); u[1] = f2bf(va.y); u[2] = f2bf(va.z); u[3] = f2bf(va.w);
        u[4] = f2bf(vb.x); u[5] = f2bf(vb.y); u[6] = f2bf(vb.z); u[7] = f2bf(vb.w);
        afrag[0][kk] = __builtin_bit_cast(bf16x8, u);
    }
#pragma unroll
    for (int kk = 0; kk < 2; ++kk) {
        float4 va = qv2[kk * 2], vb = qv2[kk * 2 + 1];
        u16x8 u;
        u[0] = f2bf(va.x); u[1] = f2bf(va.y); u[2] = f2bf(va.z); u[3] = f2bf(va.w);
        u[4] = f2bf(vb.x); u[5] = f2bf(vb.y); u[6] = f2bf(vb.z); u[7] = f2bf(vb.w);
        afrag[1][kk] = __builtin_bit_cast(bf16x8, u);
    }

    // ---- Phase 1: BD = proj @ A^T (swapped) -> col(lo)=s, row(hi*4+jr)=p.
    // Skew-store bf16 to BDs. Same wave writes & reads its own s rows.
    // This long phase also hides the 2-deep K prefetch latency.
    const unsigned short* pbase = projw + h * 64;
#pragma unroll 2
    for (int pj = 0; pj < 8; ++pj) {
        int prow = pj * 16 + lo;
        const unsigned short* pr = pbase + (size_t)prow * 512;
        bf16x8 pf0 = *(const bf16x8*)(pr + hi * 8);
        bf16x8 pf1 = *(const bf16x8*)(pr + 32 + hi * 8);
#pragma unroll
        for (int i2 = 0; i2 < 2; ++i2) {
            f32x4 acc = {0.f, 0.f, 0.f, 0.f};
            acc = __builtin_amdgcn_mfma_f32_16x16x32_bf16(pf0, afrag[i2][0], acc, 0, 0, 0);
            acc = __builtin_amdgcn_mfma_f32_16x16x32_bf16(pf1, afrag[i2][1], acc, 0, 0, 0);
            int s  = w * 32 + i2 * 16 + lo;
            int pb = pj * 16 + hi * 4;
#pragma unroll
            for (int jr = 0; jr < 4; ++jr) {
                int cw = (s + pb + jr) & 127;     // band 128 wide -> mod-128 bijection
                BDs[s * 128 + (cw ^ ((s & 7) << 3))] = f2bf(acc[jr]);
            }
        }
    }

    // ---- Main loop: 8 chunks x 32 rows, double-buffered, ONE barrier/chunk.
    size_t obase = ((size_t)((b * 8 + h) * 64 + n)) * (128 * 256);

#pragma unroll
    for (int ch = 0; ch < 8; ++ch) {
        const int buf = ch & 1;
        // stage buf from its prefetch set (vmcnt waits only for this set)
#pragma unroll
        for (int it = 0; it < 2; ++it) {
            int row = w * 8 + it * 4 + rq;        // chunk-local row 0..31
            float4 v = kpre[buf][it];
            uint2 pk;
            pk.x = pk2(v.x, v.y);
            pk.y = pk2(v.z, v.w);
            *reinterpret_cast<uint2*>(&Klds[buf][row * 64 + ((cq * 4) ^ ((row & 7) << 3))]) = pk;
        }
        // refill this set for chunk ch+2 (lands ~one chunk period later)
        if (ch < 6) {
#pragma unroll
            for (int it = 0; it < 2; ++it) {
                int row = w * 8 + it * 4 + rq;
                kpre[buf][it] =
                    *(const float4*)(kbase + (size_t)((ch + 2) * 32 + row) * 512 + cq * 4);
            }
        }
        __syncthreads();   // publishes buf; safe: last reader of buf was compute(ch-2)

        // compute the 2 cj tiles of this chunk
#pragma unroll
        for (int cjl = 0; cjl < 2; ++cjl) {
            int cj  = ch * 2 + cjl;
            int krl = cjl * 16 + lo;              // chunk-local K row
            bf16x8 kf0 = *(const bf16x8*)&Klds[buf][krl * 64 + ((hi * 8)      ^ ((krl & 7) << 3))];
            bf16x8 kf1 = *(const bf16x8*)&Klds[buf][krl * 64 + ((32 + hi * 8) ^ ((krl & 7) << 3))];
#pragma unroll
            for (int i2 = 0; i2 < 2; ++i2) {
                int stile = 2 * w + i2;
                f32x4 acc = {0.f, 0.f, 0.f, 0.f};
                acc = __builtin_amdgcn_mfma_f32_16x16x32_bf16(kf0, afrag[i2][0], acc, 0, 0, 0);
                acc = __builtin_amdgcn_mfma_f32_16x16x32_bf16(kf1, afrag[i2][1], acc, 0, 0, 0);
                int s  = stile * 16 + lo;
                int cb = cj * 16 + hi * 4;
                if (cj >= stile && cj <= stile + 8) {   // band-active (uniform/wave)
                    uint2 pk = *(const uint2*)&BDs[s * 128 + ((cb & 127) ^ ((s & 7) << 3))];
                    unsigned short v0 = (unsigned short)(pk.x & 0xffffu);
                    unsigned short v1 = (unsigned short)(pk.x >> 16);
                    unsigned short v2 = (unsigned short)(pk.y & 0xffffu);
                    unsigned short v3 = (unsigned short)(pk.y >> 16);
                    if ((unsigned)(cb + 0 - s) < 128u) acc[0] += bf2f(v0);
                    if ((unsigned)(cb + 1 - s) < 128u) acc[1] += bf2f(v1);
                    if ((unsigned)(cb + 2 - s) < 128u) acc[2] += bf2f(v2);
                    if ((unsigned)(cb + 3 - s) < 128u) acc[3] += bf2f(v3);
                }
                *reinterpret_cast<float4*>(&out[obase + (size_t)s * 256 + cb]) =
                    *reinterpret_cast<float4*>(&acc);
            }
        }
    }
}

extern "C" void kernel_launch(void* const* d_in, const int* in_sizes, int n_in,
                              void* d_out, int out_size, void* d_ws, size_t ws_size,
                              hipStream_t stream) {
    const float* Q  = (const float*)d_in[0];
    const float* Kg = (const float*)d_in[1];
    const float* W  = (const float*)d_in[2];
    float* out = (float*)d_out;
    unsigned short* projw = (unsigned short*)d_ws;   // 128*512 bf16 = 128 KB

    hipLaunchKernelGGL(proj_kernel, dim3(1024), dim3(256), 0, stream, W, projw);
    hipLaunchKernelGGL(fused_kernel, dim3(2048), dim3(256), 0, stream, Q, Kg, projw, out);
}